// Round 5
// baseline (882.529 us; speedup 1.0000x reference)
//
#include <hip/hip_runtime.h>

#pragma clang fp contract(off)

#define NPT 4096
#define B_ 16
#define S_ 1024
#define K_ 32
#define ROWS (B_*S_*K_)   // 524288
#define PNB 1024          // head layer1 partial-stats stride (slots used: NWORK)
#define NWORK 240         // worker blocks in head kernel (grid 256 = 16 fps + 240, 1 blk/CU)
#define NCHUNK 512        // 16 batches * 32 chunks of 32 queries
#define TNB 512           // fused tail grid (2 blocks/CU, all co-resident)

typedef float v2f __attribute__((ext_vector_type(2)));
typedef unsigned int u32;
typedef unsigned long long u64;
typedef __attribute__((ext_vector_type(8))) short s16x8;
typedef __attribute__((ext_vector_type(4))) float f32x4;

__device__ __forceinline__ float rlf(float v, int l) {
  return __uint_as_float(__builtin_amdgcn_readlane(__float_as_uint(v), l));
}

__device__ __forceinline__ short rne_bf16(float x) {
  u32 b = __float_as_uint(x);
  b += 0x7FFFu + ((b >> 16) & 1u);
  return (short)(b >> 16);
}
__device__ __forceinline__ u32 rne_bits(float x) {   // rounded bits, result in high 16
  u32 b = __float_as_uint(x);
  return b + 0x7FFFu + ((b >> 16) & 1u);
}

__device__ __forceinline__ f32x4 mfma16(s16x8 a, s16x8 b, f32x4 c) {
  return __builtin_amdgcn_mfma_f32_16x16x32_bf16(a, b, c, 0, 0, 0);
}

// stored-position -> original channel permutation for y2-layout tiles
__device__ __forceinline__ int permc(int p) { return ((p & 3) << 4) | (p >> 2); }

// relaxed agent atomics = sc1 load/store at the MALL coherence point.
// NO buffer_inv / buffer_wbl2 (R2 lesson: acquire/release at agent scope lower to full-L2
// invalidate / writeback on gfx950 — ~45us on the FPS critical path).
__device__ __forceinline__ void st_sc1(float* p, float v) {
  __hip_atomic_store(p, v, __ATOMIC_RELAXED, __HIP_MEMORY_SCOPE_AGENT);
}
__device__ __forceinline__ float ld_sc1(const float* p) {
  return __hip_atomic_load((float*)p, __ATOMIC_RELAXED, __HIP_MEMORY_SCOPE_AGENT);
}

// BN+relu+RNE-pack for a bf16 pair held in one dword. Bit-exact vs scalar path.
__device__ __forceinline__ u32 bnrelu_pack(u32 d, v2f sc, v2f sh) {
  v2f a;
  a.x = __uint_as_float(d << 16);
  a.y = __uint_as_float(d & 0xFFFF0000u);
  v2f z = __builtin_elementwise_fma(a, sc, sh);
  z = __builtin_elementwise_max(z, (v2f){0.f, 0.f});
  u32 zx = rne_bits(z.x), zy = rne_bits(z.y);
  return __builtin_amdgcn_perm(zy, zx, 0x07060302);   // {zx.hi16, zy.hi16}
}

template <int CTRL>
__device__ __forceinline__ u64 dpp_u64(u64 x) {
  int lo = (int)(u32)x, hi = (int)(u32)(x >> 32);
  lo = __builtin_amdgcn_update_dpp(lo, lo, CTRL, 0xF, 0xF, false);
  hi = __builtin_amdgcn_update_dpp(hi, hi, CTRL, 0xF, 0xF, false);
  return ((u64)(u32)hi << 32) | (u32)lo;
}
// full-wave f64 max -> lane 63. Keys are positive doubles => f64 order == u64 order.
__device__ __forceinline__ double wave_max_f64(double k) {
  k = fmax(k, __longlong_as_double((long long)dpp_u64<0x111>((u64)__double_as_longlong(k))));
  k = fmax(k, __longlong_as_double((long long)dpp_u64<0x112>((u64)__double_as_longlong(k))));
  k = fmax(k, __longlong_as_double((long long)dpp_u64<0x114>((u64)__double_as_longlong(k))));
  k = fmax(k, __longlong_as_double((long long)dpp_u64<0x118>((u64)__double_as_longlong(k))));
  k = fmax(k, __longlong_as_double((long long)dpp_u64<0x142>((u64)__double_as_longlong(k))));
  k = fmax(k, __longlong_as_double((long long)dpp_u64<0x143>((u64)__double_as_longlong(k))));
  return k;
}

__device__ __forceinline__ double mkkey(float d, u32 lo) {
  return __longlong_as_double((long long)(((u64)__float_as_uint(d) << 32) | lo));
}

// ---------------- HEAD: fused FPS + ball-query + layer1 (unchanged from R4) ----------------
__global__ __launch_bounds__(512, 4) void head_kernel(
    const float* __restrict__ xyz, const float* __restrict__ pts,
    const float* __restrict__ W1, const float* __restrict__ b1,
    float* __restrict__ out0, float* __restrict__ new_xyz,
    int* __restrict__ prog, unsigned short* __restrict__ y1,
    float* __restrict__ partials) {
  __shared__ float4 spt[NPT + 520]; // 64KB + pad -> LDS > 81920B => 1 block/CU
  __shared__ u64 skey[3];           // fps only
  __shared__ int sfar[S_];          // fps: selection journal; worker: gidx scratch
  __shared__ float spw[8 * 2 * 64]; // worker stats reduce
  __shared__ float snq[8][12];      // worker: per-wave query coords (sc1-loaded once/chunk)
  const int bid = blockIdx.x;
  const int t = threadIdx.x;
  const int lane = t & 63;

  if (bid < B_) {
    // ================= FPS =================
    const int b = bid;
    const float* xb = xyz + (size_t)b * 3 * NPT;
#pragma unroll
    for (int j = 0; j < 8; j++) {
      int m = t + j * 512;
      spt[m] = make_float4(xb[m], xb[NPT + m], xb[2 * NPT + m], 0.f);
    }
    if (t < 3) skey[t] = 0ull;
    const float4* xb4 = (const float4*)xb;
    float4 X0 = xb4[t * 2], X1 = xb4[t * 2 + 1];
    float4 Y0 = xb4[NPT / 4 + t * 2], Y1 = xb4[NPT / 4 + t * 2 + 1];
    float4 Z0 = xb4[2 * NPT / 4 + t * 2], Z1 = xb4[2 * NPT / 4 + t * 2 + 1];
    v2f px[4], py[4], pz[4], ds[4];
    px[0] = (v2f){X0.x, X0.y}; px[1] = (v2f){X0.z, X0.w}; px[2] = (v2f){X1.x, X1.y}; px[3] = (v2f){X1.z, X1.w};
    py[0] = (v2f){Y0.x, Y0.y}; py[1] = (v2f){Y0.z, Y0.w}; py[2] = (v2f){Y1.x, Y1.y}; py[3] = (v2f){Y1.z, Y1.w};
    pz[0] = (v2f){Z0.x, Z0.y}; pz[1] = (v2f){Z0.z, Z0.w}; pz[2] = (v2f){Z1.x, Z1.y}; pz[3] = (v2f){Z1.z, Z1.w};
    const int base = t * 8;
    u32 lo[8];
#pragma unroll
    for (int i = 0; i < 8; i++) lo[i] = ~(u32)(base + i);
#pragma unroll
    for (int j = 0; j < 4; j++) ds[j] = (v2f){1e10f, 1e10f};
    __syncthreads();
    int far = 0, slot = 0;
    for (int it = 0; it < S_; ++it) {
      if (t == 0) sfar[it] = far;
      if ((it & 31) == 0 && it != 0) {
        // deferred flag: window [it-64,it-32) stores were issued 32 iters ago -> drained
        if (t == 64 && it >= 64) {
          asm volatile("s_waitcnt vmcnt(0)" ::: "memory");
          __hip_atomic_store(&prog[b], it - 32, __ATOMIC_RELAXED, __HIP_MEMORY_SCOPE_AGENT);
        }
        // fire-and-forget issue of window [it-32,it) (wave 1 lanes 0..31)
        if (t >= 64 && t < 96) {
          int pit = it - 32 + (t - 64);
          float4 p = spt[sfar[pit]];
          size_t o = ((size_t)b * S_ + pit) * 3;
          st_sc1(&new_xyz[o + 0], p.x);
          st_sc1(&new_xyz[o + 1], p.y);
          st_sc1(&new_xyz[o + 2], p.z);
        }
      }
      float4 c = spt[far];
      v2f cx = (v2f){c.x, c.x}, cy = (v2f){c.y, c.y}, cz = (v2f){c.z, c.z};
#pragma unroll
      for (int j = 0; j < 4; j++) {
        // exact ref op order per element: ((dx*dx + dy*dy) + dz*dz), contraction OFF
        v2f dx = px[j] - cx, dy = py[j] - cy, dz = pz[j] - cz;
        v2f s = dx * dx + dy * dy;
        v2f d = s + dz * dz;
        v2f nd;
        nd.x = fminf(ds[j].x, d.x);
        nd.y = fminf(ds[j].y, d.y);
        ds[j] = nd;
      }
      // f64 sortable keys: max dist, tie -> min index (via ~idx in low word)
      double k = fmax(fmax(fmax(mkkey(ds[0].x, lo[0]), mkkey(ds[0].y, lo[1])),
                           fmax(mkkey(ds[1].x, lo[2]), mkkey(ds[1].y, lo[3]))),
                      fmax(fmax(mkkey(ds[2].x, lo[4]), mkkey(ds[2].y, lo[5])),
                           fmax(mkkey(ds[3].x, lo[6]), mkkey(ds[3].y, lo[7]))));
      k = wave_max_f64(k);
      if (lane == 63) atomicMax(&skey[slot], (u64)__double_as_longlong(k));
      __syncthreads();
      u64 kk = skey[slot];
      if (t == 0) skey[slot == 0 ? 2 : slot - 1] = 0ull;  // reset slot (it+2)%3: safe post-barrier
      far = (int)(~(u32)kk);
      slot = (slot == 2) ? 0 : slot + 1;
    }
    __syncthreads();
    // final publish on WAVE 1 (its vmcnt covers its own earlier window [960,992) stores)
    if (t >= 64 && t < 96) {
      int pit = 992 + (t - 64);
      float4 p = spt[sfar[pit]];
      size_t o = ((size_t)b * S_ + pit) * 3;
      st_sc1(&new_xyz[o + 0], p.x);
      st_sc1(&new_xyz[o + 1], p.y);
      st_sc1(&new_xyz[o + 2], p.z);
    }
    if (t == 64) {
      asm volatile("s_waitcnt vmcnt(0)" ::: "memory");
      __hip_atomic_store(&prog[b], S_, __ATOMIC_RELAXED, __HIP_MEMORY_SCOPE_AGENT);
    }
    // coalesced writeback of out0
#pragma unroll
    for (int j = 0; j < 2; j++) {
      int it = t + j * 512;
      float4 p = spt[sfar[it]];
      out0[(b * 3 + 0) * S_ + it] = p.x;
      out0[(b * 3 + 1) * S_ + it] = p.y;
      out0[(b * 3 + 2) * S_ + it] = p.z;
    }
  } else {
    // ================= WORKER: ballq + layer1 =================
    const int wv = t >> 6;
    const int grp = lane >> 3;          // 0..7; groups 0..3 gather for rows A..D
    const int gc = lane & 7;            // channel slot within group (0..5 used)
    const int wkr = bid - B_;
    float w[6];
#pragma unroll
    for (int cc = 0; cc < 6; cc++) w[cc] = W1[lane * 6 + cc];
    const float bias = b1[lane];
    float s0 = 0.f, s1 = 0.f;
    int* glds = sfar;                   // 1024 ints: [wave][4 queries][32 idx]

    for (int cid = wkr; cid < NCHUNK; cid += NWORK) {
      const int b = cid & 15, cch = cid >> 4;
      if (t == 0) {
        const int tgt = (cch + 1) * 32;
        int spins = 0;
        while (__hip_atomic_load(&prog[b], __ATOMIC_RELAXED, __HIP_MEMORY_SCOPE_AGENT) < tgt) {
          __builtin_amdgcn_s_sleep(8);
          if (++spins > (1 << 20)) break;   // fail-safe: never hang the device
        }
      }
      __syncthreads();

      // ---- ball query: 4 queries per wave, shared coordinate loads (bit-exact vs ballq) ----
      const float* xb = xyz + (size_t)b * 3 * NPT;
      const int q0 = cch * 32 + wv * 4;         // local query base in batch
      const int sg0 = b * 1024 + q0;            // global query base
      if (lane < 12)
        snq[wv][lane] = ld_sc1(&new_xyz[(size_t)sg0 * 3 + lane]);
      asm volatile("s_waitcnt vmcnt(0) lgkmcnt(0)" ::: "memory");
      float qx[4], qy[4], qz[4];
      int cnt4[4], fi[4];
#pragma unroll
      for (int j = 0; j < 4; j++) {
        qx[j] = snq[wv][j * 3 + 0];
        qy[j] = snq[wv][j * 3 + 1];
        qz[j] = snq[wv][j * 3 + 2];
        cnt4[j] = 0; fi[j] = 0x7fffffff;
      }
      const float R2 = (float)(0.4 * 0.4);
      int* gl = glds + wv * 4 * K_;
      for (int c0 = 0; c0 < NPT; c0 += 64) {
        if (cnt4[0] >= K_ && cnt4[1] >= K_ && cnt4[2] >= K_ && cnt4[3] >= K_) break;
        int n = c0 + lane;
        float x = xb[n], y = xb[NPT + n], z = xb[2 * NPT + n];
#pragma unroll
        for (int j = 0; j < 4; j++) {
          if (cnt4[j] < K_) {                   // wave-uniform guard: identical writes vs ballq
            float dx = __fadd_rn(qx[j], -x);
            float dy = __fadd_rn(qy[j], -y);
            float dz = __fadd_rn(qz[j], -z);
            float sq = __fadd_rn(__fadd_rn(__fmul_rn(dx, dx), __fmul_rn(dy, dy)), __fmul_rn(dz, dz));
            bool inr = !(sq > R2);
            unsigned long long m = __ballot(inr);
            if (inr) {
              int pos = cnt4[j] + (int)__popcll(m & ((1ull << lane) - 1ull));
              if (pos < K_) gl[j * K_ + pos] = n;
            }
            if (fi[j] == 0x7fffffff && m) fi[j] = c0 + (int)__builtin_ctzll(m);
            cnt4[j] += (int)__popcll(m);
          }
        }
      }
#pragma unroll
      for (int j = 0; j < 4; j++)
        if (lane >= cnt4[j] && lane < K_) gl[j * K_ + lane] = fi[j];
      __syncthreads();

      // ---- layer1: 4 queries x 32 rows, 4 rows per iter (bit-exact vs layer1_kernel) ----
      for (int it = 0; it < 32; ++it) {
        const int j = it >> 3, k4 = (it & 7) * 4;
        const int sg = sg0 + j;                 // global query (== rr>>5)
        float v = 0.f;
        if (grp < 4 && gc < 6) {
          int gi = gl[j * K_ + k4 + grp];
          if (gc < 3) v = xyz[((size_t)b * 3 + gc) * NPT + gi] - snq[wv][j * 3 + gc];
          else        v = pts[((size_t)b * 3 + (gc - 3)) * NPT + gi];
        }
        float acc[4];
#pragma unroll
        for (int q = 0; q < 4; q++) acc[q] = bias;
#pragma unroll
        for (int cc = 0; cc < 6; cc++) {
#pragma unroll
          for (int q = 0; q < 4; q++) acc[q] = fmaf(rlf(v, q * 8 + cc), w[cc], acc[q]);
        }
        const size_t rbase = (size_t)sg * K_ + k4;
#pragma unroll
        for (int q = 0; q < 4; q++) {
          y1[(rbase + q) * 64 + lane] = (unsigned short)rne_bf16(acc[q]);
          s0 += acc[q]; s1 = fmaf(acc[q], acc[q], s1);
        }
      }
      __syncthreads();    // protect glds before next chunk reuse
    }

    // ---- stats partials: reduce 8 waves, write slot wkr (finalize1 reads NWORK slots) ----
    spw[(wv * 2 + 0) * 64 + lane] = s0;
    spw[(wv * 2 + 1) * 64 + lane] = s1;
    __syncthreads();
    if (t < 128) {
      float p = 0.f;
#pragma unroll
      for (int ww = 0; ww < 8; ww++) p += spw[ww * 128 + t];
      partials[(size_t)t * PNB + wkr] = p;
    }
  }
}

// ---------------- fold partials -> bn scale/shift (pnb = #valid slots) ----------------
__global__ __launch_bounds__(256) void finalize_kernel(const float* __restrict__ partials,
    int cout, int pnb, const float* __restrict__ g, const float* __restrict__ be,
    float* __restrict__ bn) {
  const int c = blockIdx.x;
  const int t = threadIdx.x;
  const int lane = t & 63, wv = t >> 6;
  float s0 = 0.f, s1 = 0.f;
  for (int bb = t; bb < pnb; bb += 256) {
    s0 += partials[(size_t)c * PNB + bb];
    s1 += partials[(size_t)(cout + c) * PNB + bb];
  }
#pragma unroll
  for (int off = 32; off; off >>= 1) {
    s0 += __shfl_xor(s0, off);
    s1 += __shfl_xor(s1, off);
  }
  __shared__ float r0[4], r1[4];
  if (lane == 0) { r0[wv] = s0; r1[wv] = s1; }
  __syncthreads();
  if (t == 0) {
    double d0 = (double)r0[0] + r0[1] + r0[2] + r0[3];
    double d1 = (double)r1[0] + r1[1] + r1[2] + r1[3];
    double N = (double)ROWS;
    double mean = d0 / N;
    double var = d1 / N - mean * mean;
    double scale = (double)g[c] / sqrt(var + 1e-5);
    bn[c] = (float)scale;
    bn[cout + c] = (float)((double)be[c] - mean * scale);
  }
}

// ---------------- FUSED TAIL (R5): layer2 GEMM+y2 -> grid barrier -> bn2 -> layer3 ---------
// Grid 512 x 256, __launch_bounds__(256,2): VGPR<=256, LDS ~12KB -> 2 blocks/CU -> all 512
// co-resident (grid == capacity, same argument as head). Block-private row range
// [blk*1024,(blk+1)*1024): phase 1 writes exactly the y2 rows phase 3 reads (same CU ->
// same-XCD L2, plain loads/stores, no coherence hazard). Cross-block data = 128 stats
// floats via sc1 + device atomicAdd counter (release = per-wave vmcnt drain at barrier);
// LAST block folds part2 -> bn2g (sc1) + flag; others spin (bounded, fail-safe).
// Saves: layer2->l3fused launch gap, finalize2 launch, y2 HBM round-trip (L2-hot).
// Stats summation order differs from R3's layer2/finalize at float-rounding level only.
__global__ __launch_bounds__(256, 2) void tail_kernel(
    const unsigned short* __restrict__ y1,
    const float* __restrict__ W2, const float* __restrict__ b2,
    const float* __restrict__ bn1,
    const float* __restrict__ g2, const float* __restrict__ be2,
    const float* __restrict__ W3, const float* __restrict__ b3,
    unsigned short* __restrict__ y2,
    float* __restrict__ bn2g, int* __restrict__ cnt,
    float* __restrict__ part2, float* __restrict__ part3,
    float* __restrict__ mnbuf, float* __restrict__ mxbuf) {
  const int blk = blockIdx.x;
  const int tid = threadIdx.x;
  const int lane = tid & 63, wv = tid >> 6;
  const int quad = lane >> 4, l16 = lane & 15;
  __shared__ float sp[4 * 2 * 64];
  __shared__ float sums[128];
  __shared__ float bn2l[128];
  __shared__ int sfl[1];
  __shared__ float tmx[128 * 4], tmn[128 * 4];
  __shared__ float sp3[4 * 2 * 128];

  // ===== phase 1: layer2 (y1 -> y2) + stats over block-private tiles [blk*64,(blk+1)*64) =====
  {
    s16x8 bfrag[4][2];
    float biasr[4];
#pragma unroll
    for (int t = 0; t < 4; t++) {
      int n = l16 + 16 * t;
      biasr[t] = b2[n];
#pragma unroll
      for (int kc = 0; kc < 2; kc++)
#pragma unroll
        for (int j = 0; j < 8; j++)
          bfrag[t][kc][j] = rne_bf16(W2[(size_t)n * 64 + kc * 32 + quad * 8 + j]);
    }
    v2f sc[2][4], sh[2][4];
#pragma unroll
    for (int kc = 0; kc < 2; kc++)
#pragma unroll
      for (int p = 0; p < 4; p++) {
        int k0 = kc * 32 + quad * 8 + 2 * p;
        sc[kc][p] = (v2f){bn1[k0], bn1[k0 + 1]};
        sh[kc][p] = (v2f){bn1[64 + k0], bn1[64 + k0 + 1]};
      }
    float s0[4], s1[4];
#pragma unroll
    for (int t = 0; t < 4; t++) { s0[t] = 0.f; s1[t] = 0.f; }
    for (int j8 = 0; j8 < 8; ++j8) {
      const int mt = blk * 64 + wv * 2 + j8 * 8;
      const u32* p0 = (const u32*)(y1 + (size_t)(mt * 16 + l16) * 64 + quad * 8);
      const u32* p1 = (const u32*)(y1 + (size_t)((mt + 1) * 16 + l16) * 64 + quad * 8);
      u32 d[2][8];
#pragma unroll
      for (int q = 0; q < 4; q++) { d[0][q] = p0[q]; d[0][4 + q] = p0[16 + q]; }
#pragma unroll
      for (int q = 0; q < 4; q++) { d[1][q] = p1[q]; d[1][4 + q] = p1[16 + q]; }
      s16x8 a[2][2];
#pragma unroll
      for (int m2 = 0; m2 < 2; m2++) {
        u32* a0u = (u32*)&a[m2][0]; u32* a1u = (u32*)&a[m2][1];
#pragma unroll
        for (int q = 0; q < 4; q++) {
          a0u[q] = bnrelu_pack(d[m2][q], sc[0][q], sh[0][q]);
          a1u[q] = bnrelu_pack(d[m2][4 + q], sc[1][q], sh[1][q]);
        }
      }
      f32x4 acc[2][4];
#pragma unroll
      for (int m2 = 0; m2 < 2; m2++)
#pragma unroll
        for (int t = 0; t < 4; t++) {
          acc[m2][t] = (f32x4){biasr[t], biasr[t], biasr[t], biasr[t]};
          acc[m2][t] = mfma16(a[m2][0], bfrag[t][0], acc[m2][t]);
          acc[m2][t] = mfma16(a[m2][1], bfrag[t][1], acc[m2][t]);
        }
#pragma unroll
      for (int m2 = 0; m2 < 2; m2++) {
#pragma unroll
        for (int r = 0; r < 4; r++) {
          u32 b01 = __builtin_amdgcn_perm(rne_bits(acc[m2][1][r]), rne_bits(acc[m2][0][r]), 0x07060302);
          u32 b23 = __builtin_amdgcn_perm(rne_bits(acc[m2][3][r]), rne_bits(acc[m2][2][r]), 0x07060302);
          int m = (mt + m2) * 16 + quad * 4 + r;
          *(uint2*)(y2 + (size_t)m * 64 + 4 * l16) = make_uint2(b01, b23);
        }
#pragma unroll
        for (int t = 0; t < 4; t++)
#pragma unroll
          for (int r = 0; r < 4; r++) {
            float v = acc[m2][t][r];
            s0[t] += v; s1[t] = fmaf(v, v, s1[t]);
          }
      }
    }
#pragma unroll
    for (int t = 0; t < 4; t++) {
      s0[t] += __shfl_xor(s0[t], 16); s0[t] += __shfl_xor(s0[t], 32);
      s1[t] += __shfl_xor(s1[t], 16); s1[t] += __shfl_xor(s1[t], 32);
    }
    if (quad == 0) {
#pragma unroll
      for (int t = 0; t < 4; t++) {
        sp[wv * 128 + l16 + 16 * t] = s0[t];
        sp[wv * 128 + 64 + l16 + 16 * t] = s1[t];
      }
    }
    __syncthreads();
    if (tid < 128) {
      float p = sp[tid] + sp[128 + tid] + sp[256 + tid] + sp[384 + tid];
      st_sc1(&part2[(size_t)tid * TNB + blk], p);
    }
  }
  // each wave drains its own vmem (incl. sc1 partial stores and y2 stores) at this barrier
  __syncthreads();
  if (tid == 0) {
    int prev = atomicAdd(cnt, 1);       // device-scope, at MALL; after this block's drain
    sfl[0] = (prev == TNB - 1) ? 1 : 0;
  }
  __syncthreads();

  // ===== phase 2: bn2 (last block computes, others wait on flag) =====
  if (sfl[0]) {
    if (tid < 128) {
      float s = 0.f;
      for (int bb = 0; bb < TNB; ++bb) s += ld_sc1(&part2[(size_t)tid * TNB + bb]);
      sums[tid] = s;
    }
    __syncthreads();
    if (tid < 64) {
      double mean = (double)sums[tid] / (double)ROWS;
      double var = (double)sums[64 + tid] / (double)ROWS - mean * mean;
      double scale = (double)g2[tid] / sqrt(var + 1e-5);
      st_sc1(&bn2g[tid], (float)scale);
      st_sc1(&bn2g[64 + tid], (float)((double)be2[tid] - mean * scale));
    }
    __syncthreads();   // wave 0 drains its 128 sc1 stores before flag
    if (tid == 0)
      __hip_atomic_store(&cnt[1], 1, __ATOMIC_RELAXED, __HIP_MEMORY_SCOPE_AGENT);
  }
  if (tid == 0) {
    int spins = 0;
    while (__hip_atomic_load(&cnt[1], __ATOMIC_RELAXED, __HIP_MEMORY_SCOPE_AGENT) == 0) {
      __builtin_amdgcn_s_sleep(8);
      if (++spins > (1 << 22)) break;   // fail-safe: never hang
    }
  }
  __syncthreads();
  if (tid < 128) bn2l[tid] = ld_sc1(&bn2g[tid]);
  __syncthreads();

  // ===== phase 3: layer3 over block-private g0 in [blk*8,(blk+1)*8) (y2 L2-hot) =====
  {
    constexpr int NT = 8;
    s16x8 bfrag[NT][2];
    float biasr[NT];
#pragma unroll
    for (int t = 0; t < NT; t++) {
      int n = l16 + 16 * t;
      biasr[t] = b3[n];
#pragma unroll
      for (int kc = 0; kc < 2; kc++)
#pragma unroll
        for (int j = 0; j < 8; j++)
          bfrag[t][kc][j] = rne_bf16(W3[(size_t)n * 64 + permc(kc * 32 + quad * 8 + j)]);
    }
    v2f sc2[2][4], sh2[2][4];
#pragma unroll
    for (int kc = 0; kc < 2; kc++)
#pragma unroll
      for (int p = 0; p < 4; p++) {
        int c0 = permc(kc * 32 + quad * 8 + 2 * p);
        int c1 = permc(kc * 32 + quad * 8 + 2 * p + 1);
        sc2[kc][p] = (v2f){bn2l[c0], bn2l[c1]};
        sh2[kc][p] = (v2f){bn2l[64 + c0], bn2l[64 + c1]};
      }
    float s0[NT], s1[NT];
#pragma unroll
    for (int t = 0; t < NT; t++) { s0[t] = 0.f; s1[t] = 0.f; }
    for (int g0 = blk * 8; g0 < blk * 8 + 8; ++g0) {
      const int gq = g0 * 4 + wv;
      float mx[NT], mn[NT];
#pragma unroll
      for (int t = 0; t < NT; t++) { mx[t] = -1e30f; mn[t] = 1e30f; }
#pragma unroll
      for (int mt2 = 0; mt2 < 2; mt2++) {
        int row = gq * 32 + mt2 * 16 + l16;
        const u32* p = (const u32*)(y2 + (size_t)row * 64 + quad * 8);
        s16x8 a0, a1;
        u32* a0u = (u32*)&a0; u32* a1u = (u32*)&a1;
#pragma unroll
        for (int q = 0; q < 4; q++) {
          a0u[q] = bnrelu_pack(p[q], sc2[0][q], sh2[0][q]);
          a1u[q] = bnrelu_pack(p[16 + q], sc2[1][q], sh2[1][q]);
        }
#pragma unroll
        for (int t = 0; t < NT; t++) {
          f32x4 acc = (f32x4){biasr[t], biasr[t], biasr[t], biasr[t]};
          acc = mfma16(a0, bfrag[t][0], acc);
          acc = mfma16(a1, bfrag[t][1], acc);
#pragma unroll
          for (int r = 0; r < 4; r++) {
            float v = acc[r];
            s0[t] += v; s1[t] = fmaf(v, v, s1[t]);
            mx[t] = fmaxf(mx[t], v); mn[t] = fminf(mn[t], v);
          }
        }
      }
#pragma unroll
      for (int t = 0; t < NT; t++) {
        mx[t] = fmaxf(mx[t], __shfl_xor(mx[t], 16));
        mx[t] = fmaxf(mx[t], __shfl_xor(mx[t], 32));
        mn[t] = fminf(mn[t], __shfl_xor(mn[t], 16));
        mn[t] = fminf(mn[t], __shfl_xor(mn[t], 32));
      }
      if (quad == 0) {
#pragma unroll
        for (int t = 0; t < NT; t++) {
          tmx[(l16 + 16 * t) * 4 + wv] = mx[t];
          tmn[(l16 + 16 * t) * 4 + wv] = mn[t];
        }
      }
      __syncthreads();
      if (tid < 128) {
        int b = g0 >> 8;
        int s0i = (g0 & 255) * 4;
        size_t o = ((size_t)b * 128 + tid) * 1024 + s0i;
        *(float4*)&mxbuf[o] = *(float4*)&tmx[tid * 4];
        *(float4*)&mnbuf[o] = *(float4*)&tmn[tid * 4];
      }
      __syncthreads();
    }
#pragma unroll
    for (int t = 0; t < NT; t++) {
      s0[t] += __shfl_xor(s0[t], 16); s0[t] += __shfl_xor(s0[t], 32);
      s1[t] += __shfl_xor(s1[t], 16); s1[t] += __shfl_xor(s1[t], 32);
    }
    if (quad == 0) {
#pragma unroll
      for (int t = 0; t < NT; t++) {
        sp3[wv * 256 + l16 + 16 * t] = s0[t];
        sp3[wv * 256 + 128 + l16 + 16 * t] = s1[t];
      }
    }
    __syncthreads();
    {
      float p = sp3[tid] + sp3[256 + tid] + sp3[512 + tid] + sp3[768 + tid];
      part3[(size_t)tid * TNB + blk] = p;   // plain: consumed by next kernel
    }
  }
}

// ---------------- fused finalize3 + apply: each block covers exactly ONE channel ------------
__global__ __launch_bounds__(256) void l3final_kernel(
    const float* __restrict__ part3, const float* __restrict__ g,
    const float* __restrict__ be, const float* __restrict__ mnbuf,
    const float* __restrict__ mxbuf, float* __restrict__ out1) {
  const int t = threadIdx.x;
  const int ch = (blockIdx.x >> 2) & 127;
  const int lane = t & 63, wv = t >> 6;
  float s0 = 0.f, s1 = 0.f;
  for (int bb = t; bb < TNB; bb += 256) {
    s0 += part3[(size_t)ch * TNB + bb];
    s1 += part3[(size_t)(128 + ch) * TNB + bb];
  }
#pragma unroll
  for (int off = 32; off; off >>= 1) {
    s0 += __shfl_xor(s0, off);
    s1 += __shfl_xor(s1, off);
  }
  __shared__ float r0[4], r1[4];
  __shared__ float bnsh[2];
  if (lane == 0) { r0[wv] = s0; r1[wv] = s1; }
  __syncthreads();
  if (t == 0) {
    double d0 = (double)r0[0] + r0[1] + r0[2] + r0[3];
    double d1 = (double)r1[0] + r1[1] + r1[2] + r1[3];
    double N = (double)ROWS;
    double mean = d0 / N;
    double var = d1 / N - mean * mean;
    double scale = (double)g[ch] / sqrt(var + 1e-5);
    bnsh[0] = (float)scale;
    bnsh[1] = (float)((double)be[ch] - mean * scale);
  }
  __syncthreads();
  float s = bnsh[0], h = bnsh[1];
  int i = blockIdx.x * 256 + t;
  float v = (s > 0.f) ? mxbuf[i] : mnbuf[i];
  out1[i] = fmaxf(fmaf(v, s, h), 0.f);
}

extern "C" void kernel_launch(void* const* d_in, const int* in_sizes, int n_in,
                              void* d_out, int out_size, void* d_ws, size_t ws_size,
                              hipStream_t stream) {
  const float* xyz = (const float*)d_in[0];
  const float* pts = (const float*)d_in[1];
  const float* W1 = (const float*)d_in[2],  *b1 = (const float*)d_in[3];
  const float* g1 = (const float*)d_in[4],  *be1 = (const float*)d_in[5];
  const float* W2 = (const float*)d_in[6],  *b2 = (const float*)d_in[7];
  const float* g2 = (const float*)d_in[8],  *be2 = (const float*)d_in[9];
  const float* W3 = (const float*)d_in[10], *b3 = (const float*)d_in[11];
  const float* g3 = (const float*)d_in[12], *be3 = (const float*)d_in[13];
  float* out0 = (float*)d_out;                 // xyz_query_pc [16,3,1024]
  float* out1 = out0 + B_ * 3 * S_;            // new_points   [16,128,1024]

  char* ws = (char*)d_ws;
  float* new_xyz  = (float*)(ws);
  float* bn1      = (float*)(ws + 196608);
  float* bn2g     = bn1 + 128;
  int*   prog     = (int*)(ws + 198656);                           // prog[0..15], cnt = prog[16..17]
  int*   cnt      = prog + 16;
  float* partials = (float*)(ws + 2295808);                        // head layer1 stats (128 x PNB)
  float* part2    = (float*)(ws + 2295808 + 524288);               // 128 x TNB
  float* part3    = (float*)(ws + 2295808 + 524288 + 262144);      // 256 x TNB
  unsigned short* y1 = (unsigned short*)(ws + 4392960);            // 64 MB bf16
  unsigned short* y2 = (unsigned short*)(ws + 4392960 + 67108864); // 64 MB bf16 (K-permuted)
  // mn/mx alias y1: y1 is dead after tail phase 1, which the tail's grid barrier orders
  // before any phase-3 write. Next replay rewrites y1 (head) before any read.
  float* mnbuf = (float*)(ws + 4392960);
  float* mxbuf = (float*)(ws + 4392960 + 8388608);

  hipMemsetAsync(prog, 0, 128, stream);   // reset progress flags + tail counter each replay
  head_kernel<<<B_ + NWORK, 512, 0, stream>>>(xyz, pts, W1, b1, out0, new_xyz, prog, y1, partials);
  finalize_kernel<<<64, 256, 0, stream>>>(partials, 64, NWORK, g1, be1, bn1);
  tail_kernel<<<TNB, 256, 0, stream>>>(y1, W2, b2, bn1, g2, be2, W3, b3, y2,
                                       bn2g, cnt, part2, part3, mnbuf, mxbuf);
  l3final_kernel<<<8192, 256, 0, stream>>>(part3, g3, be3, mnbuf, mxbuf, out1);
}

// Round 6
// 873.077 us; speedup vs baseline: 1.0108x; 1.0108x over previous
//
#include <hip/hip_runtime.h>

#pragma clang fp contract(off)

#define NPT 4096
#define B_ 16
#define S_ 1024
#define K_ 32
#define ROWS (B_*S_*K_)   // 524288
#define NWORK 240         // worker blocks in head kernel (grid 256 = 16 fps + 240, 1 blk/CU)
#define NCHUNK 512        // 16 batches * 32 chunks of 32 queries
#define PNB 1024          // layer2 / l3fused grid

typedef float v2f __attribute__((ext_vector_type(2)));
typedef unsigned int u32;
typedef unsigned long long u64;
typedef __attribute__((ext_vector_type(8))) short s16x8;
typedef __attribute__((ext_vector_type(4))) float f32x4;

__device__ __forceinline__ float rlf(float v, int l) {
  return __uint_as_float(__builtin_amdgcn_readlane(__float_as_uint(v), l));
}

__device__ __forceinline__ short rne_bf16(float x) {
  u32 b = __float_as_uint(x);
  b += 0x7FFFu + ((b >> 16) & 1u);
  return (short)(b >> 16);
}
__device__ __forceinline__ u32 rne_bits(float x) {   // rounded bits, result in high 16
  u32 b = __float_as_uint(x);
  return b + 0x7FFFu + ((b >> 16) & 1u);
}

__device__ __forceinline__ f32x4 mfma16(s16x8 a, s16x8 b, f32x4 c) {
  return __builtin_amdgcn_mfma_f32_16x16x32_bf16(a, b, c, 0, 0, 0);
}

// stored-position -> original channel permutation for y2-layout tiles
__device__ __forceinline__ int permc(int p) { return ((p & 3) << 4) | (p >> 2); }

// relaxed agent atomics = sc1 load/store at the MALL coherence point.
// NO buffer_inv / buffer_wbl2 (R2 lesson: acquire/release at agent scope lower to full-L2
// invalidate / writeback on gfx950 — ~45us on the FPS critical path).
__device__ __forceinline__ void st_sc1(float* p, float v) {
  __hip_atomic_store(p, v, __ATOMIC_RELAXED, __HIP_MEMORY_SCOPE_AGENT);
}
__device__ __forceinline__ float ld_sc1(const float* p) {
  return __hip_atomic_load((float*)p, __ATOMIC_RELAXED, __HIP_MEMORY_SCOPE_AGENT);
}

// BN+relu+RNE-pack for a bf16 pair held in one dword. Bit-exact vs scalar path.
__device__ __forceinline__ u32 bnrelu_pack(u32 d, v2f sc, v2f sh) {
  v2f a;
  a.x = __uint_as_float(d << 16);
  a.y = __uint_as_float(d & 0xFFFF0000u);
  v2f z = __builtin_elementwise_fma(a, sc, sh);
  z = __builtin_elementwise_max(z, (v2f){0.f, 0.f});
  u32 zx = rne_bits(z.x), zy = rne_bits(z.y);
  return __builtin_amdgcn_perm(zy, zx, 0x07060302);   // {zx.hi16, zy.hi16}
}

template <int CTRL>
__device__ __forceinline__ u64 dpp_u64(u64 x) {
  int lo = (int)(u32)x, hi = (int)(u32)(x >> 32);
  lo = __builtin_amdgcn_update_dpp(lo, lo, CTRL, 0xF, 0xF, false);
  hi = __builtin_amdgcn_update_dpp(hi, hi, CTRL, 0xF, 0xF, false);
  return ((u64)(u32)hi << 32) | (u32)lo;
}
// full-wave f64 max -> lane 63. Keys are positive doubles => f64 order == u64 order.
__device__ __forceinline__ double wave_max_f64(double k) {
  k = fmax(k, __longlong_as_double((long long)dpp_u64<0x111>((u64)__double_as_longlong(k))));
  k = fmax(k, __longlong_as_double((long long)dpp_u64<0x112>((u64)__double_as_longlong(k))));
  k = fmax(k, __longlong_as_double((long long)dpp_u64<0x114>((u64)__double_as_longlong(k))));
  k = fmax(k, __longlong_as_double((long long)dpp_u64<0x118>((u64)__double_as_longlong(k))));
  k = fmax(k, __longlong_as_double((long long)dpp_u64<0x142>((u64)__double_as_longlong(k))));
  k = fmax(k, __longlong_as_double((long long)dpp_u64<0x143>((u64)__double_as_longlong(k))));
  return k;
}

__device__ __forceinline__ double mkkey(float d, u32 lo) {
  return __longlong_as_double((long long)(((u64)__float_as_uint(d) << 32) | lo));
}

// ---------------- HEAD: fused FPS + ball-query + layer1 + inline bn1 ----------------
// FPS core and worker structure unchanged (R3/R4 — proven ~663-666us, pinned by whole-chip
// clock droop; DO NOT touch). R6 change: workers atomicAdd their folded 128 stats into
// global sums1 (device-scope, MALL); LAST worker (completion counter) computes bn1 inline.
// finalize1 launch eliminated. Visibility to layer2 via end-of-dispatch release.
__global__ __launch_bounds__(512, 4) void head_kernel(
    const float* __restrict__ xyz, const float* __restrict__ pts,
    const float* __restrict__ W1, const float* __restrict__ b1,
    const float* __restrict__ g1, const float* __restrict__ be1,
    float* __restrict__ out0, float* __restrict__ new_xyz,
    int* __restrict__ prog, int* __restrict__ cnt,
    unsigned short* __restrict__ y1,
    float* __restrict__ sums1, float* __restrict__ bn1) {
  __shared__ float4 spt[NPT + 520]; // 64KB + pad -> LDS > 81920B => 1 block/CU
  __shared__ u64 skey[3];           // fps only
  __shared__ int sfar[S_];          // fps: selection journal; worker: gidx scratch
  __shared__ float spw[8 * 2 * 64]; // worker stats reduce
  __shared__ float snq[8][12];      // worker: per-wave query coords (sc1-loaded once/chunk)
  __shared__ int lastw;
  const int bid = blockIdx.x;
  const int t = threadIdx.x;
  const int lane = t & 63;

  if (bid < B_) {
    // ================= FPS =================
    const int b = bid;
    const float* xb = xyz + (size_t)b * 3 * NPT;
#pragma unroll
    for (int j = 0; j < 8; j++) {
      int m = t + j * 512;
      spt[m] = make_float4(xb[m], xb[NPT + m], xb[2 * NPT + m], 0.f);
    }
    if (t < 3) skey[t] = 0ull;
    const float4* xb4 = (const float4*)xb;
    float4 X0 = xb4[t * 2], X1 = xb4[t * 2 + 1];
    float4 Y0 = xb4[NPT / 4 + t * 2], Y1 = xb4[NPT / 4 + t * 2 + 1];
    float4 Z0 = xb4[2 * NPT / 4 + t * 2], Z1 = xb4[2 * NPT / 4 + t * 2 + 1];
    v2f px[4], py[4], pz[4], ds[4];
    px[0] = (v2f){X0.x, X0.y}; px[1] = (v2f){X0.z, X0.w}; px[2] = (v2f){X1.x, X1.y}; px[3] = (v2f){X1.z, X1.w};
    py[0] = (v2f){Y0.x, Y0.y}; py[1] = (v2f){Y0.z, Y0.w}; py[2] = (v2f){Y1.x, Y1.y}; py[3] = (v2f){Y1.z, Y1.w};
    pz[0] = (v2f){Z0.x, Z0.y}; pz[1] = (v2f){Z0.z, Z0.w}; pz[2] = (v2f){Z1.x, Z1.y}; pz[3] = (v2f){Z1.z, Z1.w};
    const int base = t * 8;
    u32 lo[8];
#pragma unroll
    for (int i = 0; i < 8; i++) lo[i] = ~(u32)(base + i);
#pragma unroll
    for (int j = 0; j < 4; j++) ds[j] = (v2f){1e10f, 1e10f};
    __syncthreads();
    int far = 0, slot = 0;
    for (int it = 0; it < S_; ++it) {
      if (t == 0) sfar[it] = far;
      if ((it & 31) == 0 && it != 0) {
        // deferred flag: window [it-64,it-32) stores were issued 32 iters ago -> drained
        if (t == 64 && it >= 64) {
          asm volatile("s_waitcnt vmcnt(0)" ::: "memory");
          __hip_atomic_store(&prog[b], it - 32, __ATOMIC_RELAXED, __HIP_MEMORY_SCOPE_AGENT);
        }
        // fire-and-forget issue of window [it-32,it) (wave 1 lanes 0..31)
        if (t >= 64 && t < 96) {
          int pit = it - 32 + (t - 64);
          float4 p = spt[sfar[pit]];
          size_t o = ((size_t)b * S_ + pit) * 3;
          st_sc1(&new_xyz[o + 0], p.x);
          st_sc1(&new_xyz[o + 1], p.y);
          st_sc1(&new_xyz[o + 2], p.z);
        }
      }
      float4 c = spt[far];
      v2f cx = (v2f){c.x, c.x}, cy = (v2f){c.y, c.y}, cz = (v2f){c.z, c.z};
#pragma unroll
      for (int j = 0; j < 4; j++) {
        // exact ref op order per element: ((dx*dx + dy*dy) + dz*dz), contraction OFF
        v2f dx = px[j] - cx, dy = py[j] - cy, dz = pz[j] - cz;
        v2f s = dx * dx + dy * dy;
        v2f d = s + dz * dz;
        v2f nd;
        nd.x = fminf(ds[j].x, d.x);
        nd.y = fminf(ds[j].y, d.y);
        ds[j] = nd;
      }
      // f64 sortable keys: max dist, tie -> min index (via ~idx in low word)
      double k = fmax(fmax(fmax(mkkey(ds[0].x, lo[0]), mkkey(ds[0].y, lo[1])),
                           fmax(mkkey(ds[1].x, lo[2]), mkkey(ds[1].y, lo[3]))),
                      fmax(fmax(mkkey(ds[2].x, lo[4]), mkkey(ds[2].y, lo[5])),
                           fmax(mkkey(ds[3].x, lo[6]), mkkey(ds[3].y, lo[7]))));
      k = wave_max_f64(k);
      if (lane == 63) atomicMax(&skey[slot], (u64)__double_as_longlong(k));
      __syncthreads();
      u64 kk = skey[slot];
      if (t == 0) skey[slot == 0 ? 2 : slot - 1] = 0ull;  // reset slot (it+2)%3: safe post-barrier
      far = (int)(~(u32)kk);
      slot = (slot == 2) ? 0 : slot + 1;
    }
    __syncthreads();
    // final publish on WAVE 1 (its vmcnt covers its own earlier window [960,992) stores)
    if (t >= 64 && t < 96) {
      int pit = 992 + (t - 64);
      float4 p = spt[sfar[pit]];
      size_t o = ((size_t)b * S_ + pit) * 3;
      st_sc1(&new_xyz[o + 0], p.x);
      st_sc1(&new_xyz[o + 1], p.y);
      st_sc1(&new_xyz[o + 2], p.z);
    }
    if (t == 64) {
      asm volatile("s_waitcnt vmcnt(0)" ::: "memory");
      __hip_atomic_store(&prog[b], S_, __ATOMIC_RELAXED, __HIP_MEMORY_SCOPE_AGENT);
    }
    // coalesced writeback of out0
#pragma unroll
    for (int j = 0; j < 2; j++) {
      int it = t + j * 512;
      float4 p = spt[sfar[it]];
      out0[(b * 3 + 0) * S_ + it] = p.x;
      out0[(b * 3 + 1) * S_ + it] = p.y;
      out0[(b * 3 + 2) * S_ + it] = p.z;
    }
  } else {
    // ================= WORKER: ballq + layer1 =================
    const int wv = t >> 6;
    const int grp = lane >> 3;          // 0..7; groups 0..3 gather for rows A..D
    const int gc = lane & 7;            // channel slot within group (0..5 used)
    const int wkr = bid - B_;
    float w[6];
#pragma unroll
    for (int cc = 0; cc < 6; cc++) w[cc] = W1[lane * 6 + cc];
    const float bias = b1[lane];
    float s0 = 0.f, s1 = 0.f;
    int* glds = sfar;                   // 1024 ints: [wave][4 queries][32 idx]

    for (int cid = wkr; cid < NCHUNK; cid += NWORK) {
      const int b = cid & 15, cch = cid >> 4;
      if (t == 0) {
        const int tgt = (cch + 1) * 32;
        int spins = 0;
        while (__hip_atomic_load(&prog[b], __ATOMIC_RELAXED, __HIP_MEMORY_SCOPE_AGENT) < tgt) {
          __builtin_amdgcn_s_sleep(8);
          if (++spins > (1 << 20)) break;   // fail-safe: never hang the device
        }
      }
      __syncthreads();

      // ---- ball query: 4 queries per wave, shared coordinate loads (bit-exact vs ballq) ----
      const float* xb = xyz + (size_t)b * 3 * NPT;
      const int q0 = cch * 32 + wv * 4;         // local query base in batch
      const int sg0 = b * 1024 + q0;            // global query base
      if (lane < 12)
        snq[wv][lane] = ld_sc1(&new_xyz[(size_t)sg0 * 3 + lane]);
      asm volatile("s_waitcnt vmcnt(0) lgkmcnt(0)" ::: "memory");
      float qx[4], qy[4], qz[4];
      int cnt4[4], fi[4];
#pragma unroll
      for (int j = 0; j < 4; j++) {
        qx[j] = snq[wv][j * 3 + 0];
        qy[j] = snq[wv][j * 3 + 1];
        qz[j] = snq[wv][j * 3 + 2];
        cnt4[j] = 0; fi[j] = 0x7fffffff;
      }
      const float R2 = (float)(0.4 * 0.4);
      int* gl = glds + wv * 4 * K_;
      for (int c0 = 0; c0 < NPT; c0 += 64) {
        if (cnt4[0] >= K_ && cnt4[1] >= K_ && cnt4[2] >= K_ && cnt4[3] >= K_) break;
        int n = c0 + lane;
        float x = xb[n], y = xb[NPT + n], z = xb[2 * NPT + n];
#pragma unroll
        for (int j = 0; j < 4; j++) {
          if (cnt4[j] < K_) {                   // wave-uniform guard: identical writes vs ballq
            float dx = __fadd_rn(qx[j], -x);
            float dy = __fadd_rn(qy[j], -y);
            float dz = __fadd_rn(qz[j], -z);
            float sq = __fadd_rn(__fadd_rn(__fmul_rn(dx, dx), __fmul_rn(dy, dy)), __fmul_rn(dz, dz));
            bool inr = !(sq > R2);
            unsigned long long m = __ballot(inr);
            if (inr) {
              int pos = cnt4[j] + (int)__popcll(m & ((1ull << lane) - 1ull));
              if (pos < K_) gl[j * K_ + pos] = n;
            }
            if (fi[j] == 0x7fffffff && m) fi[j] = c0 + (int)__builtin_ctzll(m);
            cnt4[j] += (int)__popcll(m);
          }
        }
      }
#pragma unroll
      for (int j = 0; j < 4; j++)
        if (lane >= cnt4[j] && lane < K_) gl[j * K_ + lane] = fi[j];
      __syncthreads();

      // ---- layer1: 4 queries x 32 rows, 4 rows per iter (bit-exact vs layer1_kernel) ----
      for (int it = 0; it < 32; ++it) {
        const int j = it >> 3, k4 = (it & 7) * 4;
        const int sg = sg0 + j;                 // global query (== rr>>5)
        float v = 0.f;
        if (grp < 4 && gc < 6) {
          int gi = gl[j * K_ + k4 + grp];
          if (gc < 3) v = xyz[((size_t)b * 3 + gc) * NPT + gi] - snq[wv][j * 3 + gc];
          else        v = pts[((size_t)b * 3 + (gc - 3)) * NPT + gi];
        }
        float acc[4];
#pragma unroll
        for (int q = 0; q < 4; q++) acc[q] = bias;
#pragma unroll
        for (int cc = 0; cc < 6; cc++) {
#pragma unroll
          for (int q = 0; q < 4; q++) acc[q] = fmaf(rlf(v, q * 8 + cc), w[cc], acc[q]);
        }
        const size_t rbase = (size_t)sg * K_ + k4;
#pragma unroll
        for (int q = 0; q < 4; q++) {
          y1[(rbase + q) * 64 + lane] = (unsigned short)rne_bf16(acc[q]);
          s0 += acc[q]; s1 = fmaf(acc[q], acc[q], s1);
        }
      }
      __syncthreads();    // protect glds before next chunk reuse
    }

    // ---- stats: LDS-fold 8 waves -> atomicAdd to sums1; LAST worker computes bn1 inline ----
    spw[(wv * 2 + 0) * 64 + lane] = s0;
    spw[(wv * 2 + 1) * 64 + lane] = s1;
    __syncthreads();
    if (t < 128) {
      float p = 0.f;
#pragma unroll
      for (int ww = 0; ww < 8; ww++) p += spw[ww * 128 + t];
      atomicAdd(&sums1[t], p);
    }
    asm volatile("s_waitcnt vmcnt(0)" ::: "memory");  // my adds acked at MALL
    __syncthreads();
    if (t == 0) {
      int prev = atomicAdd(&cnt[0], 1);               // MALL-ordered after the drains
      lastw = (prev == NWORK - 1) ? 1 : 0;
    }
    __syncthreads();
    if (lastw && t < 64) {
      float a0 = ld_sc1(&sums1[t]), a1 = ld_sc1(&sums1[64 + t]);
      double mean = (double)a0 / (double)ROWS;
      double var = (double)a1 / (double)ROWS - mean * mean;
      double scale = (double)g1[t] / sqrt(var + 1e-5);
      bn1[t] = (float)scale;                          // plain store: end-of-dispatch release
      bn1[64 + t] = (float)((double)be1[t] - mean * scale);
    }
  }
}

// ---------------- Layer 2 (MFMA): bn1+relu -> GEMM 64->64 -> y2; inline bn2 (R6) ----------
// GEMM/stores identical to R3's layer2_kernel. Stats: LDS fold (identical block partial),
// then atomicAdd into sums2; LAST block (counter) computes bn2 inline. finalize2 eliminated.
__global__ __launch_bounds__(256) void layer2_kernel(
    const unsigned short* __restrict__ y1, const float* __restrict__ W,
    const float* __restrict__ bias, const float* __restrict__ bnin,
    const float* __restrict__ g2, const float* __restrict__ be2,
    unsigned short* __restrict__ y2, float* __restrict__ sums2,
    int* __restrict__ cnt, float* __restrict__ bn2) {
  constexpr int NT = 4;
  const int lane = threadIdx.x & 63, wv = threadIdx.x >> 6;
  const int quad = lane >> 4, l16 = lane & 15;
  __shared__ int lastb;
  s16x8 bfrag[NT][2];
  float biasr[NT];
#pragma unroll
  for (int t = 0; t < NT; t++) {
    int n = l16 + 16 * t;
    biasr[t] = bias[n];
#pragma unroll
    for (int kc = 0; kc < 2; kc++)
#pragma unroll
      for (int j = 0; j < 8; j++)
        bfrag[t][kc][j] = rne_bf16(W[(size_t)n * 64 + kc * 32 + quad * 8 + j]);
  }
  v2f sc2[2][4], sh2[2][4];
#pragma unroll
  for (int kc = 0; kc < 2; kc++)
#pragma unroll
    for (int p = 0; p < 4; p++) {
      int k0 = kc * 32 + quad * 8 + 2 * p;
      sc2[kc][p] = (v2f){bnin[k0], bnin[k0 + 1]};
      sh2[kc][p] = (v2f){bnin[64 + k0], bnin[64 + k0 + 1]};
    }
  float s0[NT], s1[NT];
#pragma unroll
  for (int t = 0; t < NT; t++) { s0[t] = 0.f; s1[t] = 0.f; }
  const int nwaves = gridDim.x * 4;
  for (int mt = (blockIdx.x * 4 + wv) * 2; mt < ROWS / 16; mt += nwaves * 2) {
    const u32* p0 = (const u32*)(y1 + (size_t)(mt * 16 + l16) * 64 + quad * 8);
    const u32* p1 = (const u32*)(y1 + (size_t)((mt + 1) * 16 + l16) * 64 + quad * 8);
    u32 d[2][8];
#pragma unroll
    for (int q = 0; q < 4; q++) { d[0][q] = p0[q]; d[0][4 + q] = p0[16 + q]; }
#pragma unroll
    for (int q = 0; q < 4; q++) { d[1][q] = p1[q]; d[1][4 + q] = p1[16 + q]; }
    s16x8 a[2][2];
#pragma unroll
    for (int m2 = 0; m2 < 2; m2++) {
      u32* a0u = (u32*)&a[m2][0]; u32* a1u = (u32*)&a[m2][1];
#pragma unroll
      for (int q = 0; q < 4; q++) {
        a0u[q] = bnrelu_pack(d[m2][q], sc2[0][q], sh2[0][q]);
        a1u[q] = bnrelu_pack(d[m2][4 + q], sc2[1][q], sh2[1][q]);
      }
    }
    f32x4 acc[2][NT];
#pragma unroll
    for (int m2 = 0; m2 < 2; m2++)
#pragma unroll
      for (int t = 0; t < NT; t++) {
        acc[m2][t] = (f32x4){biasr[t], biasr[t], biasr[t], biasr[t]};
        acc[m2][t] = mfma16(a[m2][0], bfrag[t][0], acc[m2][t]);
        acc[m2][t] = mfma16(a[m2][1], bfrag[t][1], acc[m2][t]);
      }
#pragma unroll
    for (int m2 = 0; m2 < 2; m2++) {
#pragma unroll
      for (int r = 0; r < 4; r++) {
        u32 b01 = __builtin_amdgcn_perm(rne_bits(acc[m2][1][r]), rne_bits(acc[m2][0][r]), 0x07060302);
        u32 b23 = __builtin_amdgcn_perm(rne_bits(acc[m2][3][r]), rne_bits(acc[m2][2][r]), 0x07060302);
        int m = (mt + m2) * 16 + quad * 4 + r;
        *(uint2*)(y2 + (size_t)m * 64 + 4 * l16) = make_uint2(b01, b23);
      }
#pragma unroll
      for (int t = 0; t < NT; t++)
#pragma unroll
        for (int r = 0; r < 4; r++) {
          float v = acc[m2][t][r];
          s0[t] += v; s1[t] = fmaf(v, v, s1[t]);
        }
    }
  }
#pragma unroll
  for (int t = 0; t < NT; t++) {
    s0[t] += __shfl_xor(s0[t], 16); s0[t] += __shfl_xor(s0[t], 32);
    s1[t] += __shfl_xor(s1[t], 16); s1[t] += __shfl_xor(s1[t], 32);
  }
  __shared__ float sp[4 * 2 * 64];
  if (quad == 0) {
#pragma unroll
    for (int t = 0; t < NT; t++) {
      sp[wv * 128 + l16 + 16 * t] = s0[t];
      sp[wv * 128 + 64 + l16 + 16 * t] = s1[t];
    }
  }
  __syncthreads();
  if (threadIdx.x < 128) {
    int tt = threadIdx.x;
    float p = sp[tt] + sp[128 + tt] + sp[256 + tt] + sp[384 + tt];
    atomicAdd(&sums2[tt], p);
  }
  asm volatile("s_waitcnt vmcnt(0)" ::: "memory");
  __syncthreads();
  if (threadIdx.x == 0) {
    int prev = atomicAdd(&cnt[1], 1);
    lastb = (prev == (int)gridDim.x - 1) ? 1 : 0;
  }
  __syncthreads();
  if (lastb && threadIdx.x < 64) {
    int tt = threadIdx.x;
    float a0 = ld_sc1(&sums2[tt]), a1 = ld_sc1(&sums2[64 + tt]);
    double mean = (double)a0 / (double)ROWS;
    double var = (double)a1 / (double)ROWS - mean * mean;
    double scale = (double)g2[tt] / sqrt(var + 1e-5);
    bn2[tt] = (float)scale;
    bn2[64 + tt] = (float)((double)be2[tt] - mean * scale);
  }
}

// ---------------- Fused layer3: GEMM (y2, permuted-K) -> min/max + stats->atomicAdd --------
__global__ __launch_bounds__(256) void l3fused_kernel(
    const unsigned short* __restrict__ y2, const float* __restrict__ W3,
    const float* __restrict__ b3, const float* __restrict__ bn2,
    float* __restrict__ mnbuf, float* __restrict__ mxbuf,   // [b][ch][s] f32
    float* __restrict__ sums3) {
  constexpr int NT = 8;
  const int lane = threadIdx.x & 63, wv = threadIdx.x >> 6;
  const int quad = lane >> 4, l16 = lane & 15;
  s16x8 bfrag[NT][2];
  float biasr[NT];
#pragma unroll
  for (int t = 0; t < NT; t++) {
    int n = l16 + 16 * t;
    biasr[t] = b3[n];
#pragma unroll
    for (int kc = 0; kc < 2; kc++)
#pragma unroll
      for (int j = 0; j < 8; j++)
        bfrag[t][kc][j] = rne_bf16(W3[(size_t)n * 64 + permc(kc * 32 + quad * 8 + j)]);
  }
  v2f sc2[2][4], sh2[2][4];
#pragma unroll
  for (int kc = 0; kc < 2; kc++)
#pragma unroll
    for (int p = 0; p < 4; p++) {
      int c0 = permc(kc * 32 + quad * 8 + 2 * p);
      int c1 = permc(kc * 32 + quad * 8 + 2 * p + 1);
      sc2[kc][p] = (v2f){bn2[c0], bn2[c1]};
      sh2[kc][p] = (v2f){bn2[64 + c0], bn2[64 + c1]};
    }
  float s0[NT], s1[NT];
#pragma unroll
  for (int t = 0; t < NT; t++) { s0[t] = 0.f; s1[t] = 0.f; }
  __shared__ float tmx[128 * 4], tmn[128 * 4];
  for (int g0 = blockIdx.x; g0 < 4096; g0 += 1024) {
    const int gq = g0 * 4 + wv;
    float mx[NT], mn[NT];
#pragma unroll
    for (int t = 0; t < NT; t++) { mx[t] = -1e30f; mn[t] = 1e30f; }
#pragma unroll
    for (int mt2 = 0; mt2 < 2; mt2++) {
      int row = gq * 32 + mt2 * 16 + l16;
      const u32* p = (const u32*)(y2 + (size_t)row * 64 + quad * 8);
      s16x8 a0, a1;
      u32* a0u = (u32*)&a0; u32* a1u = (u32*)&a1;
#pragma unroll
      for (int q = 0; q < 4; q++) {
        a0u[q] = bnrelu_pack(p[q], sc2[0][q], sh2[0][q]);
        a1u[q] = bnrelu_pack(p[16 + q], sc2[1][q], sh2[1][q]);
      }
#pragma unroll
      for (int t = 0; t < NT; t++) {
        f32x4 acc = (f32x4){biasr[t], biasr[t], biasr[t], biasr[t]};
        acc = mfma16(a0, bfrag[t][0], acc);
        acc = mfma16(a1, bfrag[t][1], acc);
#pragma unroll
        for (int r = 0; r < 4; r++) {
          float v = acc[r];
          s0[t] += v; s1[t] = fmaf(v, v, s1[t]);
          mx[t] = fmaxf(mx[t], v); mn[t] = fminf(mn[t], v);
        }
      }
    }
#pragma unroll
    for (int t = 0; t < NT; t++) {
      mx[t] = fmaxf(mx[t], __shfl_xor(mx[t], 16));
      mx[t] = fmaxf(mx[t], __shfl_xor(mx[t], 32));
      mn[t] = fminf(mn[t], __shfl_xor(mn[t], 16));
      mn[t] = fminf(mn[t], __shfl_xor(mn[t], 32));
    }
    if (quad == 0) {
#pragma unroll
      for (int t = 0; t < NT; t++) {
        tmx[(l16 + 16 * t) * 4 + wv] = mx[t];
        tmn[(l16 + 16 * t) * 4 + wv] = mn[t];
      }
    }
    __syncthreads();
    if (threadIdx.x < 128) {
      int b = g0 >> 8;
      int s0i = (g0 & 255) * 4;
      size_t o = ((size_t)b * 128 + threadIdx.x) * 1024 + s0i;
      *(float4*)&mxbuf[o] = *(float4*)&tmx[threadIdx.x * 4];
      *(float4*)&mnbuf[o] = *(float4*)&tmn[threadIdx.x * 4];
    }
    __syncthreads();
  }
#pragma unroll
  for (int t = 0; t < NT; t++) {
    s0[t] += __shfl_xor(s0[t], 16); s0[t] += __shfl_xor(s0[t], 32);
    s1[t] += __shfl_xor(s1[t], 16); s1[t] += __shfl_xor(s1[t], 32);
  }
  __shared__ float sp[4 * 2 * 128];
  if (quad == 0) {
#pragma unroll
    for (int t = 0; t < NT; t++) {
      sp[wv * 256 + l16 + 16 * t] = s0[t];
      sp[wv * 256 + 128 + l16 + 16 * t] = s1[t];
    }
  }
  __syncthreads();
  {
    int tt = threadIdx.x;
    float p = sp[tt] + sp[256 + tt] + sp[512 + tt] + sp[768 + tt];
    atomicAdd(&sums3[tt], p);   // folded by NO ONE: l3final reads sums directly
  }
}

// ---------------- finalize3 + apply (R6): bn3 from sums3 (2 loads), no partials fold ------
__global__ __launch_bounds__(256) void l3final_kernel(
    const float* __restrict__ sums3, const float* __restrict__ g,
    const float* __restrict__ be, const float* __restrict__ mnbuf,
    const float* __restrict__ mxbuf, float* __restrict__ out1) {
  const int t = threadIdx.x;
  const int ch = (blockIdx.x >> 2) & 127;
  __shared__ float bnsh[2];
  if (t == 0) {
    double d0 = (double)sums3[ch];
    double d1 = (double)sums3[128 + ch];
    double N = (double)ROWS;
    double mean = d0 / N;
    double var = d1 / N - mean * mean;
    double scale = (double)g[ch] / sqrt(var + 1e-5);
    bnsh[0] = (float)scale;
    bnsh[1] = (float)((double)be[ch] - mean * scale);
  }
  __syncthreads();
  float s = bnsh[0], h = bnsh[1];
  int i = blockIdx.x * 256 + t;
  float v = (s > 0.f) ? mxbuf[i] : mnbuf[i];
  out1[i] = fmaxf(fmaf(v, s, h), 0.f);
}

extern "C" void kernel_launch(void* const* d_in, const int* in_sizes, int n_in,
                              void* d_out, int out_size, void* d_ws, size_t ws_size,
                              hipStream_t stream) {
  const float* xyz = (const float*)d_in[0];
  const float* pts = (const float*)d_in[1];
  const float* W1 = (const float*)d_in[2],  *b1 = (const float*)d_in[3];
  const float* g1 = (const float*)d_in[4],  *be1 = (const float*)d_in[5];
  const float* W2 = (const float*)d_in[6],  *b2 = (const float*)d_in[7];
  const float* g2 = (const float*)d_in[8],  *be2 = (const float*)d_in[9];
  const float* W3 = (const float*)d_in[10], *b3 = (const float*)d_in[11];
  const float* g3 = (const float*)d_in[12], *be3 = (const float*)d_in[13];
  float* out0 = (float*)d_out;                 // xyz_query_pc [16,3,1024]
  float* out1 = out0 + B_ * 3 * S_;            // new_points   [16,128,1024]

  char* ws = (char*)d_ws;
  float* new_xyz = (float*)(ws);                                   // 196608 B
  float* bn1     = (float*)(ws + 196608);                          // 128 f
  float* bn2     = bn1 + 128;                                      // 128 f
  int*   prog    = (int*)(ws + 198656);                            // 16 ints
  int*   cnt     = prog + 16;                                      // 4 ints
  float* sums1   = (float*)(ws + 198784);                          // 128 f
  float* sums2   = sums1 + 128;                                    // 128 f
  float* sums3   = sums2 + 128;                                    // 256 f (ends 200832)
  unsigned short* y1 = (unsigned short*)(ws + 4392960);            // 64 MB bf16
  unsigned short* y2 = (unsigned short*)(ws + 4392960 + 67108864); // 64 MB bf16 (K-permuted)
  // mn/mx alias y1 (dead after layer2); y1 rewritten by head before any read next replay
  float* mnbuf = (float*)(ws + 4392960);
  float* mxbuf = (float*)(ws + 4392960 + 8388608);

  // zero prog flags + counters + all atomic-accumulated sums each replay
  hipMemsetAsync(prog, 0, 2560, stream);
  head_kernel<<<B_ + NWORK, 512, 0, stream>>>(xyz, pts, W1, b1, g1, be1, out0, new_xyz,
                                              prog, cnt, y1, sums1, bn1);
  layer2_kernel<<<PNB, 256, 0, stream>>>(y1, W2, b2, bn1, g2, be2, y2, sums2, cnt, bn2);
  l3fused_kernel<<<PNB, 256, 0, stream>>>(y2, W3, b3, bn2, mnbuf, mxbuf, sums3);
  l3final_kernel<<<8192, 256, 0, stream>>>(sums3, g3, be3, mnbuf, mxbuf, out1);
}

// Round 8
// 849.693 us; speedup vs baseline: 1.0386x; 1.0275x over previous
//
#include <hip/hip_runtime.h>

#pragma clang fp contract(off)

#define NPT 4096
#define B_ 16
#define S_ 1024
#define K_ 32
#define ROWS (B_*S_*K_)   // 524288
#define NWORK 240         // worker blocks in head kernel (grid 256 = 16 fps + 240, 1 blk/CU)
#define NCHUNK 512        // 16 batches * 32 chunks of 32 queries
#define PNB 1024          // layer2 / l3fused grid
#define NBKT 8            // stats atomic buckets (R7: fixes R6's 1024-way MALL contention)

typedef float v2f __attribute__((ext_vector_type(2)));
typedef unsigned int u32;
typedef unsigned long long u64;
typedef __attribute__((ext_vector_type(8))) short s16x8;
typedef __attribute__((ext_vector_type(4))) float f32x4;

__device__ __forceinline__ float rlf(float v, int l) {
  return __uint_as_float(__builtin_amdgcn_readlane(__float_as_uint(v), l));
}

__device__ __forceinline__ short rne_bf16(float x) {
  u32 b = __float_as_uint(x);
  b += 0x7FFFu + ((b >> 16) & 1u);
  return (short)(b >> 16);
}
__device__ __forceinline__ u32 rne_bits(float x) {   // rounded bits, result in high 16
  u32 b = __float_as_uint(x);
  return b + 0x7FFFu + ((b >> 16) & 1u);
}

__device__ __forceinline__ f32x4 mfma16(s16x8 a, s16x8 b, f32x4 c) {
  return __builtin_amdgcn_mfma_f32_16x16x32_bf16(a, b, c, 0, 0, 0);
}

// stored-position -> original channel permutation for y2-layout tiles
__device__ __forceinline__ int permc(int p) { return ((p & 3) << 4) | (p >> 2); }

// relaxed agent atomics = sc1 load/store at the MALL coherence point.
// NO buffer_inv / buffer_wbl2 (R2 lesson: acquire/release at agent scope lower to full-L2
// invalidate / writeback on gfx950 — ~45us on the FPS critical path).
__device__ __forceinline__ void st_sc1(float* p, float v) {
  __hip_atomic_store(p, v, __ATOMIC_RELAXED, __HIP_MEMORY_SCOPE_AGENT);
}
__device__ __forceinline__ float ld_sc1(const float* p) {
  return __hip_atomic_load((float*)p, __ATOMIC_RELAXED, __HIP_MEMORY_SCOPE_AGENT);
}

// BN+relu+RNE-pack for a bf16 pair held in one dword. Bit-exact vs scalar path.
__device__ __forceinline__ u32 bnrelu_pack(u32 d, v2f sc, v2f sh) {
  v2f a;
  a.x = __uint_as_float(d << 16);
  a.y = __uint_as_float(d & 0xFFFF0000u);
  v2f z = __builtin_elementwise_fma(a, sc, sh);
  z = __builtin_elementwise_max(z, (v2f){0.f, 0.f});
  u32 zx = rne_bits(z.x), zy = rne_bits(z.y);
  return __builtin_amdgcn_perm(zy, zx, 0x07060302);   // {zx.hi16, zy.hi16}
}

template <int CTRL>
__device__ __forceinline__ u64 dpp_u64(u64 x) {
  int lo = (int)(u32)x, hi = (int)(u32)(x >> 32);
  lo = __builtin_amdgcn_update_dpp(lo, lo, CTRL, 0xF, 0xF, false);
  hi = __builtin_amdgcn_update_dpp(hi, hi, CTRL, 0xF, 0xF, false);
  return ((u64)(u32)hi << 32) | (u32)lo;
}
// full-wave f64 max -> lane 63. Keys are positive doubles => f64 order == u64 order.
__device__ __forceinline__ double wave_max_f64(double k) {
  k = fmax(k, __longlong_as_double((long long)dpp_u64<0x111>((u64)__double_as_longlong(k))));
  k = fmax(k, __longlong_as_double((long long)dpp_u64<0x112>((u64)__double_as_longlong(k))));
  k = fmax(k, __longlong_as_double((long long)dpp_u64<0x114>((u64)__double_as_longlong(k))));
  k = fmax(k, __longlong_as_double((long long)dpp_u64<0x118>((u64)__double_as_longlong(k))));
  k = fmax(k, __longlong_as_double((long long)dpp_u64<0x142>((u64)__double_as_longlong(k))));
  k = fmax(k, __longlong_as_double((long long)dpp_u64<0x143>((u64)__double_as_longlong(k))));
  return k;
}

__device__ __forceinline__ double mkkey(float d, u32 lo) {
  return __longlong_as_double((long long)(((u64)__float_as_uint(d) << 32) | lo));
}

// ---------------- HEAD: fused FPS + ball-query + layer1 + inline bn1 (unchanged R6) -------
// FPS core and worker structure FINAL (~663-667us, pinned by whole-chip clock droop across
// 4 publish schemes R3-R6 — DO NOT touch). Workers atomicAdd folded stats into sums1 (240
// staggered contenders, hidden in head's shadow); LAST worker computes bn1 inline.
__global__ __launch_bounds__(512, 4) void head_kernel(
    const float* __restrict__ xyz, const float* __restrict__ pts,
    const float* __restrict__ W1, const float* __restrict__ b1,
    const float* __restrict__ g1, const float* __restrict__ be1,
    float* __restrict__ out0, float* __restrict__ new_xyz,
    int* __restrict__ prog, int* __restrict__ cnt,
    unsigned short* __restrict__ y1,
    float* __restrict__ sums1, float* __restrict__ bn1) {
  __shared__ float4 spt[NPT + 520]; // 64KB + pad -> LDS > 81920B => 1 block/CU
  __shared__ u64 skey[3];           // fps only
  __shared__ int sfar[S_];          // fps: selection journal; worker: gidx scratch
  __shared__ float spw[8 * 2 * 64]; // worker stats reduce
  __shared__ float snq[8][12];      // worker: per-wave query coords (sc1-loaded once/chunk)
  __shared__ int lastw;
  const int bid = blockIdx.x;
  const int t = threadIdx.x;
  const int lane = t & 63;

  if (bid < B_) {
    // ================= FPS =================
    const int b = bid;
    const float* xb = xyz + (size_t)b * 3 * NPT;
#pragma unroll
    for (int j = 0; j < 8; j++) {
      int m = t + j * 512;
      spt[m] = make_float4(xb[m], xb[NPT + m], xb[2 * NPT + m], 0.f);
    }
    if (t < 3) skey[t] = 0ull;
    const float4* xb4 = (const float4*)xb;
    float4 X0 = xb4[t * 2], X1 = xb4[t * 2 + 1];
    float4 Y0 = xb4[NPT / 4 + t * 2], Y1 = xb4[NPT / 4 + t * 2 + 1];
    float4 Z0 = xb4[2 * NPT / 4 + t * 2], Z1 = xb4[2 * NPT / 4 + t * 2 + 1];
    v2f px[4], py[4], pz[4], ds[4];
    px[0] = (v2f){X0.x, X0.y}; px[1] = (v2f){X0.z, X0.w}; px[2] = (v2f){X1.x, X1.y}; px[3] = (v2f){X1.z, X1.w};
    py[0] = (v2f){Y0.x, Y0.y}; py[1] = (v2f){Y0.z, Y0.w}; py[2] = (v2f){Y1.x, Y1.y}; py[3] = (v2f){Y1.z, Y1.w};
    pz[0] = (v2f){Z0.x, Z0.y}; pz[1] = (v2f){Z0.z, Z0.w}; pz[2] = (v2f){Z1.x, Z1.y}; pz[3] = (v2f){Z1.z, Z1.w};
    const int base = t * 8;
    u32 lo[8];
#pragma unroll
    for (int i = 0; i < 8; i++) lo[i] = ~(u32)(base + i);
#pragma unroll
    for (int j = 0; j < 4; j++) ds[j] = (v2f){1e10f, 1e10f};
    __syncthreads();
    int far = 0, slot = 0;
    for (int it = 0; it < S_; ++it) {
      if (t == 0) sfar[it] = far;
      if ((it & 31) == 0 && it != 0) {
        // deferred flag: window [it-64,it-32) stores were issued 32 iters ago -> drained
        if (t == 64 && it >= 64) {
          asm volatile("s_waitcnt vmcnt(0)" ::: "memory");
          __hip_atomic_store(&prog[b], it - 32, __ATOMIC_RELAXED, __HIP_MEMORY_SCOPE_AGENT);
        }
        // fire-and-forget issue of window [it-32,it) (wave 1 lanes 0..31)
        if (t >= 64 && t < 96) {
          int pit = it - 32 + (t - 64);
          float4 p = spt[sfar[pit]];
          size_t o = ((size_t)b * S_ + pit) * 3;
          st_sc1(&new_xyz[o + 0], p.x);
          st_sc1(&new_xyz[o + 1], p.y);
          st_sc1(&new_xyz[o + 2], p.z);
        }
      }
      float4 c = spt[far];
      v2f cx = (v2f){c.x, c.x}, cy = (v2f){c.y, c.y}, cz = (v2f){c.z, c.z};
#pragma unroll
      for (int j = 0; j < 4; j++) {
        // exact ref op order per element: ((dx*dx + dy*dy) + dz*dz), contraction OFF
        v2f dx = px[j] - cx, dy = py[j] - cy, dz = pz[j] - cz;
        v2f s = dx * dx + dy * dy;
        v2f d = s + dz * dz;
        v2f nd;
        nd.x = fminf(ds[j].x, d.x);
        nd.y = fminf(ds[j].y, d.y);
        ds[j] = nd;
      }
      // f64 sortable keys: max dist, tie -> min index (via ~idx in low word)
      double k = fmax(fmax(fmax(mkkey(ds[0].x, lo[0]), mkkey(ds[0].y, lo[1])),
                           fmax(mkkey(ds[1].x, lo[2]), mkkey(ds[1].y, lo[3]))),
                      fmax(fmax(mkkey(ds[2].x, lo[4]), mkkey(ds[2].y, lo[5])),
                           fmax(mkkey(ds[3].x, lo[6]), mkkey(ds[3].y, lo[7]))));
      k = wave_max_f64(k);
      if (lane == 63) atomicMax(&skey[slot], (u64)__double_as_longlong(k));
      __syncthreads();
      u64 kk = skey[slot];
      if (t == 0) skey[slot == 0 ? 2 : slot - 1] = 0ull;  // reset slot (it+2)%3: safe post-barrier
      far = (int)(~(u32)kk);
      slot = (slot == 2) ? 0 : slot + 1;
    }
    __syncthreads();
    // final publish on WAVE 1 (its vmcnt covers its own earlier window [960,992) stores)
    if (t >= 64 && t < 96) {
      int pit = 992 + (t - 64);
      float4 p = spt[sfar[pit]];
      size_t o = ((size_t)b * S_ + pit) * 3;
      st_sc1(&new_xyz[o + 0], p.x);
      st_sc1(&new_xyz[o + 1], p.y);
      st_sc1(&new_xyz[o + 2], p.z);
    }
    if (t == 64) {
      asm volatile("s_waitcnt vmcnt(0)" ::: "memory");
      __hip_atomic_store(&prog[b], S_, __ATOMIC_RELAXED, __HIP_MEMORY_SCOPE_AGENT);
    }
    // coalesced writeback of out0
#pragma unroll
    for (int j = 0; j < 2; j++) {
      int it = t + j * 512;
      float4 p = spt[sfar[it]];
      out0[(b * 3 + 0) * S_ + it] = p.x;
      out0[(b * 3 + 1) * S_ + it] = p.y;
      out0[(b * 3 + 2) * S_ + it] = p.z;
    }
  } else {
    // ================= WORKER: ballq + layer1 =================
    const int wv = t >> 6;
    const int grp = lane >> 3;          // 0..7; groups 0..3 gather for rows A..D
    const int gc = lane & 7;            // channel slot within group (0..5 used)
    const int wkr = bid - B_;
    float w[6];
#pragma unroll
    for (int cc = 0; cc < 6; cc++) w[cc] = W1[lane * 6 + cc];
    const float bias = b1[lane];
    float s0 = 0.f, s1 = 0.f;
    int* glds = sfar;                   // 1024 ints: [wave][4 queries][32 idx]

    for (int cid = wkr; cid < NCHUNK; cid += NWORK) {
      const int b = cid & 15, cch = cid >> 4;
      if (t == 0) {
        const int tgt = (cch + 1) * 32;
        int spins = 0;
        while (__hip_atomic_load(&prog[b], __ATOMIC_RELAXED, __HIP_MEMORY_SCOPE_AGENT) < tgt) {
          __builtin_amdgcn_s_sleep(8);
          if (++spins > (1 << 20)) break;   // fail-safe: never hang the device
        }
      }
      __syncthreads();

      // ---- ball query: 4 queries per wave, shared coordinate loads (bit-exact vs ballq) ----
      const float* xb = xyz + (size_t)b * 3 * NPT;
      const int q0 = cch * 32 + wv * 4;         // local query base in batch
      const int sg0 = b * 1024 + q0;            // global query base
      if (lane < 12)
        snq[wv][lane] = ld_sc1(&new_xyz[(size_t)sg0 * 3 + lane]);
      asm volatile("s_waitcnt vmcnt(0) lgkmcnt(0)" ::: "memory");
      float qx[4], qy[4], qz[4];
      int cnt4[4], fi[4];
#pragma unroll
      for (int j = 0; j < 4; j++) {
        qx[j] = snq[wv][j * 3 + 0];
        qy[j] = snq[wv][j * 3 + 1];
        qz[j] = snq[wv][j * 3 + 2];
        cnt4[j] = 0; fi[j] = 0x7fffffff;
      }
      const float R2 = (float)(0.4 * 0.4);
      int* gl = glds + wv * 4 * K_;
      for (int c0 = 0; c0 < NPT; c0 += 64) {
        if (cnt4[0] >= K_ && cnt4[1] >= K_ && cnt4[2] >= K_ && cnt4[3] >= K_) break;
        int n = c0 + lane;
        float x = xb[n], y = xb[NPT + n], z = xb[2 * NPT + n];
#pragma unroll
        for (int j = 0; j < 4; j++) {
          if (cnt4[j] < K_) {                   // wave-uniform guard: identical writes vs ballq
            float dx = __fadd_rn(qx[j], -x);
            float dy = __fadd_rn(qy[j], -y);
            float dz = __fadd_rn(qz[j], -z);
            float sq = __fadd_rn(__fadd_rn(__fmul_rn(dx, dx), __fmul_rn(dy, dy)), __fmul_rn(dz, dz));
            bool inr = !(sq > R2);
            unsigned long long m = __ballot(inr);
            if (inr) {
              int pos = cnt4[j] + (int)__popcll(m & ((1ull << lane) - 1ull));
              if (pos < K_) gl[j * K_ + pos] = n;
            }
            if (fi[j] == 0x7fffffff && m) fi[j] = c0 + (int)__builtin_ctzll(m);
            cnt4[j] += (int)__popcll(m);
          }
        }
      }
#pragma unroll
      for (int j = 0; j < 4; j++)
        if (lane >= cnt4[j] && lane < K_) gl[j * K_ + lane] = fi[j];
      __syncthreads();

      // ---- layer1: 4 queries x 32 rows, 4 rows per iter (bit-exact vs layer1_kernel) ----
      for (int it = 0; it < 32; ++it) {
        const int j = it >> 3, k4 = (it & 7) * 4;
        const int sg = sg0 + j;                 // global query (== rr>>5)
        float v = 0.f;
        if (grp < 4 && gc < 6) {
          int gi = gl[j * K_ + k4 + grp];
          if (gc < 3) v = xyz[((size_t)b * 3 + gc) * NPT + gi] - snq[wv][j * 3 + gc];
          else        v = pts[((size_t)b * 3 + (gc - 3)) * NPT + gi];
        }
        float acc[4];
#pragma unroll
        for (int q = 0; q < 4; q++) acc[q] = bias;
#pragma unroll
        for (int cc = 0; cc < 6; cc++) {
#pragma unroll
          for (int q = 0; q < 4; q++) acc[q] = fmaf(rlf(v, q * 8 + cc), w[cc], acc[q]);
        }
        const size_t rbase = (size_t)sg * K_ + k4;
#pragma unroll
        for (int q = 0; q < 4; q++) {
          y1[(rbase + q) * 64 + lane] = (unsigned short)rne_bf16(acc[q]);
          s0 += acc[q]; s1 = fmaf(acc[q], acc[q], s1);
        }
      }
      __syncthreads();    // protect glds before next chunk reuse
    }

    // ---- stats: LDS-fold 8 waves -> atomicAdd to sums1; LAST worker computes bn1 inline ----
    spw[(wv * 2 + 0) * 64 + lane] = s0;
    spw[(wv * 2 + 1) * 64 + lane] = s1;
    __syncthreads();
    if (t < 128) {
      float p = 0.f;
#pragma unroll
      for (int ww = 0; ww < 8; ww++) p += spw[ww * 128 + t];
      atomicAdd(&sums1[t], p);
    }
    asm volatile("s_waitcnt vmcnt(0)" ::: "memory");  // my adds acked at MALL
    __syncthreads();
    if (t == 0) {
      int prev = atomicAdd(&cnt[0], 1);               // MALL-ordered after the drains
      lastw = (prev == NWORK - 1) ? 1 : 0;
    }
    __syncthreads();
    if (lastw && t < 64) {
      float a0 = ld_sc1(&sums1[t]), a1 = ld_sc1(&sums1[64 + t]);
      double mean = (double)a0 / (double)ROWS;
      double var = (double)a1 / (double)ROWS - mean * mean;
      double scale = (double)g1[t] / sqrt(var + 1e-5);
      bn1[t] = (float)scale;                          // plain store: end-of-dispatch release
      bn1[64 + t] = (float)((double)be1[t] - mean * scale);
    }
  }
}

// ---------------- Layer 2 (MFMA): bn1+relu -> GEMM 64->64 -> y2; inline bn2 (R7) ----------
// GEMM/stores identical to R3. Stats: LDS fold, then atomicAdd into BUCKETED sums2
// (bucket = blockIdx&7 -> 128-way contention instead of R6's 1024-way MALL hotspot);
// LAST block folds 8 buckets (16 sc1 loads) and computes bn2 inline.
__global__ __launch_bounds__(256) void layer2_kernel(
    const unsigned short* __restrict__ y1, const float* __restrict__ W,
    const float* __restrict__ bias, const float* __restrict__ bnin,
    const float* __restrict__ g2, const float* __restrict__ be2,
    unsigned short* __restrict__ y2, float* __restrict__ sums2,
    int* __restrict__ cnt, float* __restrict__ bn2) {
  constexpr int NT = 4;
  const int lane = threadIdx.x & 63, wv = threadIdx.x >> 6;
  const int quad = lane >> 4, l16 = lane & 15;
  __shared__ int lastb;
  s16x8 bfrag[NT][2];
  float biasr[NT];
#pragma unroll
  for (int t = 0; t < NT; t++) {
    int n = l16 + 16 * t;
    biasr[t] = bias[n];
#pragma unroll
    for (int kc = 0; kc < 2; kc++)
#pragma unroll
      for (int j = 0; j < 8; j++)
        bfrag[t][kc][j] = rne_bf16(W[(size_t)n * 64 + kc * 32 + quad * 8 + j]);
  }
  v2f sc2[2][4], sh2[2][4];
#pragma unroll
  for (int kc = 0; kc < 2; kc++)
#pragma unroll
    for (int p = 0; p < 4; p++) {
      int k0 = kc * 32 + quad * 8 + 2 * p;
      sc2[kc][p] = (v2f){bnin[k0], bnin[k0 + 1]};
      sh2[kc][p] = (v2f){bnin[64 + k0], bnin[64 + k0 + 1]};
    }
  float s0[NT], s1[NT];
#pragma unroll
  for (int t = 0; t < NT; t++) { s0[t] = 0.f; s1[t] = 0.f; }
  const int nwaves = gridDim.x * 4;
  for (int mt = (blockIdx.x * 4 + wv) * 2; mt < ROWS / 16; mt += nwaves * 2) {
    const u32* p0 = (const u32*)(y1 + (size_t)(mt * 16 + l16) * 64 + quad * 8);
    const u32* p1 = (const u32*)(y1 + (size_t)((mt + 1) * 16 + l16) * 64 + quad * 8);
    u32 d[2][8];
#pragma unroll
    for (int q = 0; q < 4; q++) { d[0][q] = p0[q]; d[0][4 + q] = p0[16 + q]; }
#pragma unroll
    for (int q = 0; q < 4; q++) { d[1][q] = p1[q]; d[1][4 + q] = p1[16 + q]; }
    s16x8 a[2][2];
#pragma unroll
    for (int m2 = 0; m2 < 2; m2++) {
      u32* a0u = (u32*)&a[m2][0]; u32* a1u = (u32*)&a[m2][1];
#pragma unroll
      for (int q = 0; q < 4; q++) {
        a0u[q] = bnrelu_pack(d[m2][q], sc2[0][q], sh2[0][q]);
        a1u[q] = bnrelu_pack(d[m2][4 + q], sc2[1][q], sh2[1][q]);
      }
    }
    f32x4 acc[2][NT];
#pragma unroll
    for (int m2 = 0; m2 < 2; m2++)
#pragma unroll
      for (int t = 0; t < NT; t++) {
        acc[m2][t] = (f32x4){biasr[t], biasr[t], biasr[t], biasr[t]};
        acc[m2][t] = mfma16(a[m2][0], bfrag[t][0], acc[m2][t]);
        acc[m2][t] = mfma16(a[m2][1], bfrag[t][1], acc[m2][t]);
      }
#pragma unroll
    for (int m2 = 0; m2 < 2; m2++) {
#pragma unroll
      for (int r = 0; r < 4; r++) {
        u32 b01 = __builtin_amdgcn_perm(rne_bits(acc[m2][1][r]), rne_bits(acc[m2][0][r]), 0x07060302);
        u32 b23 = __builtin_amdgcn_perm(rne_bits(acc[m2][3][r]), rne_bits(acc[m2][2][r]), 0x07060302);
        int m = (mt + m2) * 16 + quad * 4 + r;
        *(uint2*)(y2 + (size_t)m * 64 + 4 * l16) = make_uint2(b01, b23);
      }
#pragma unroll
      for (int t = 0; t < NT; t++)
#pragma unroll
        for (int r = 0; r < 4; r++) {
          float v = acc[m2][t][r];
          s0[t] += v; s1[t] = fmaf(v, v, s1[t]);
        }
    }
  }
#pragma unroll
  for (int t = 0; t < NT; t++) {
    s0[t] += __shfl_xor(s0[t], 16); s0[t] += __shfl_xor(s0[t], 32);
    s1[t] += __shfl_xor(s1[t], 16); s1[t] += __shfl_xor(s1[t], 32);
  }
  __shared__ float sp[4 * 2 * 64];
  if (quad == 0) {
#pragma unroll
    for (int t = 0; t < NT; t++) {
      sp[wv * 128 + l16 + 16 * t] = s0[t];
      sp[wv * 128 + 64 + l16 + 16 * t] = s1[t];
    }
  }
  __syncthreads();
  if (threadIdx.x < 128) {
    int tt = threadIdx.x;
    float p = sp[tt] + sp[128 + tt] + sp[256 + tt] + sp[384 + tt];
    atomicAdd(&sums2[(blockIdx.x & (NBKT - 1)) * 128 + tt], p);
  }
  asm volatile("s_waitcnt vmcnt(0)" ::: "memory");
  __syncthreads();
  if (threadIdx.x == 0) {
    int prev = atomicAdd(&cnt[1], 1);
    lastb = (prev == (int)gridDim.x - 1) ? 1 : 0;
  }
  __syncthreads();
  if (lastb && threadIdx.x < 64) {
    int tt = threadIdx.x;
    float a0 = 0.f, a1 = 0.f;
#pragma unroll
    for (int i = 0; i < NBKT; i++) {
      a0 += ld_sc1(&sums2[i * 128 + tt]);
      a1 += ld_sc1(&sums2[i * 128 + 64 + tt]);
    }
    double mean = (double)a0 / (double)ROWS;
    double var = (double)a1 / (double)ROWS - mean * mean;
    double scale = (double)g2[tt] / sqrt(var + 1e-5);
    bn2[tt] = (float)scale;
    bn2[64 + tt] = (float)((double)be2[tt] - mean * scale);
  }
}

// ---------------- Fused layer3: GEMM (y2, permuted-K) -> min/max + bucketed stats ----------
__global__ __launch_bounds__(256) void l3fused_kernel(
    const unsigned short* __restrict__ y2, const float* __restrict__ W3,
    const float* __restrict__ b3, const float* __restrict__ bn2,
    float* __restrict__ mnbuf, float* __restrict__ mxbuf,   // [b][ch][s] f32
    float* __restrict__ sums3) {
  constexpr int NT = 8;
  const int lane = threadIdx.x & 63, wv = threadIdx.x >> 6;
  const int quad = lane >> 4, l16 = lane & 15;
  s16x8 bfrag[NT][2];
  float biasr[NT];
#pragma unroll
  for (int t = 0; t < NT; t++) {
    int n = l16 + 16 * t;
    biasr[t] = b3[n];
#pragma unroll
    for (int kc = 0; kc < 2; kc++)
#pragma unroll
      for (int j = 0; j < 8; j++)
        bfrag[t][kc][j] = rne_bf16(W3[(size_t)n * 64 + permc(kc * 32 + quad * 8 + j)]);
  }
  v2f sc2[2][4], sh2[2][4];
#pragma unroll
  for (int kc = 0; kc < 2; kc++)
#pragma unroll
    for (int p = 0; p < 4; p++) {
      int c0 = permc(kc * 32 + quad * 8 + 2 * p);
      int c1 = permc(kc * 32 + quad * 8 + 2 * p + 1);
      sc2[kc][p] = (v2f){bn2[c0], bn2[c1]};
      sh2[kc][p] = (v2f){bn2[64 + c0], bn2[64 + c1]};
    }
  float s0[NT], s1[NT];
#pragma unroll
  for (int t = 0; t < NT; t++) { s0[t] = 0.f; s1[t] = 0.f; }
  __shared__ float tmx[128 * 4], tmn[128 * 4];
  for (int g0 = blockIdx.x; g0 < 4096; g0 += 1024) {
    const int gq = g0 * 4 + wv;
    float mx[NT], mn[NT];
#pragma unroll
    for (int t = 0; t < NT; t++) { mx[t] = -1e30f; mn[t] = 1e30f; }
#pragma unroll
    for (int mt2 = 0; mt2 < 2; mt2++) {
      int row = gq * 32 + mt2 * 16 + l16;
      const u32* p = (const u32*)(y2 + (size_t)row * 64 + quad * 8);
      s16x8 a0, a1;
      u32* a0u = (u32*)&a0; u32* a1u = (u32*)&a1;
#pragma unroll
      for (int q = 0; q < 4; q++) {
        a0u[q] = bnrelu_pack(p[q], sc2[0][q], sh2[0][q]);
        a1u[q] = bnrelu_pack(p[16 + q], sc2[1][q], sh2[1][q]);
      }
#pragma unroll
      for (int t = 0; t < NT; t++) {
        f32x4 acc = (f32x4){biasr[t], biasr[t], biasr[t], biasr[t]};
        acc = mfma16(a0, bfrag[t][0], acc);
        acc = mfma16(a1, bfrag[t][1], acc);
#pragma unroll
        for (int r = 0; r < 4; r++) {
          float v = acc[r];
          s0[t] += v; s1[t] = fmaf(v, v, s1[t]);
          mx[t] = fmaxf(mx[t], v); mn[t] = fminf(mn[t], v);
        }
      }
    }
#pragma unroll
    for (int t = 0; t < NT; t++) {
      mx[t] = fmaxf(mx[t], __shfl_xor(mx[t], 16));
      mx[t] = fmaxf(mx[t], __shfl_xor(mx[t], 32));
      mn[t] = fminf(mn[t], __shfl_xor(mn[t], 16));
      mn[t] = fminf(mn[t], __shfl_xor(mn[t], 32));
    }
    if (quad == 0) {
#pragma unroll
      for (int t = 0; t < NT; t++) {
        tmx[(l16 + 16 * t) * 4 + wv] = mx[t];
        tmn[(l16 + 16 * t) * 4 + wv] = mn[t];
      }
    }
    __syncthreads();
    if (threadIdx.x < 128) {
      int b = g0 >> 8;
      int s0i = (g0 & 255) * 4;
      size_t o = ((size_t)b * 128 + threadIdx.x) * 1024 + s0i;
      *(float4*)&mxbuf[o] = *(float4*)&tmx[threadIdx.x * 4];
      *(float4*)&mnbuf[o] = *(float4*)&tmn[threadIdx.x * 4];
    }
    __syncthreads();
  }
#pragma unroll
  for (int t = 0; t < NT; t++) {
    s0[t] += __shfl_xor(s0[t], 16); s0[t] += __shfl_xor(s0[t], 32);
    s1[t] += __shfl_xor(s1[t], 16); s1[t] += __shfl_xor(s1[t], 32);
  }
  __shared__ float sp[4 * 2 * 128];
  if (quad == 0) {
#pragma unroll
    for (int t = 0; t < NT; t++) {
      sp[wv * 256 + l16 + 16 * t] = s0[t];
      sp[wv * 256 + 128 + l16 + 16 * t] = s1[t];
    }
  }
  __syncthreads();
  {
    int tt = threadIdx.x;
    float p = sp[tt] + sp[256 + tt] + sp[512 + tt] + sp[768 + tt];
    atomicAdd(&sums3[(blockIdx.x & (NBKT - 1)) * 256 + tt], p);  // bucketed; l3final folds 8
  }
}

// ---------------- finalize3 + apply: bn3 from 8 buckets (16 loads), then elementwise ------
__global__ __launch_bounds__(256) void l3final_kernel(
    const float* __restrict__ sums3, const float* __restrict__ g,
    const float* __restrict__ be, const float* __restrict__ mnbuf,
    const float* __restrict__ mxbuf, float* __restrict__ out1) {
  const int t = threadIdx.x;
  const int ch = (blockIdx.x >> 2) & 127;
  __shared__ float bnsh[2];
  if (t == 0) {
    double d0 = 0.0, d1 = 0.0;
#pragma unroll
    for (int i = 0; i < NBKT; i++) {
      d0 += (double)sums3[i * 256 + ch];
      d1 += (double)sums3[i * 256 + 128 + ch];
    }
    double N = (double)ROWS;
    double mean = d0 / N;
    double var = d1 / N - mean * mean;
    double scale = (double)g[ch] / sqrt(var + 1e-5);
    bnsh[0] = (float)scale;
    bnsh[1] = (float)((double)be[ch] - mean * scale);
  }
  __syncthreads();
  float s = bnsh[0], h = bnsh[1];
  int i = blockIdx.x * 256 + t;
  float v = (s > 0.f) ? mxbuf[i] : mnbuf[i];
  out1[i] = fmaxf(fmaf(v, s, h), 0.f);
}

extern "C" void kernel_launch(void* const* d_in, const int* in_sizes, int n_in,
                              void* d_out, int out_size, void* d_ws, size_t ws_size,
                              hipStream_t stream) {
  const float* xyz = (const float*)d_in[0];
  const float* pts = (const float*)d_in[1];
  const float* W1 = (const float*)d_in[2],  *b1 = (const float*)d_in[3];
  const float* g1 = (const float*)d_in[4],  *be1 = (const float*)d_in[5];
  const float* W2 = (const float*)d_in[6],  *b2 = (const float*)d_in[7];
  const float* g2 = (const float*)d_in[8],  *be2 = (const float*)d_in[9];
  const float* W3 = (const float*)d_in[10], *b3 = (const float*)d_in[11];
  const float* g3 = (const float*)d_in[12], *be3 = (const float*)d_in[13];
  float* out0 = (float*)d_out;                 // xyz_query_pc [16,3,1024]
  float* out1 = out0 + B_ * 3 * S_;            // new_points   [16,128,1024]

  char* ws = (char*)d_ws;
  float* new_xyz = (float*)(ws);                                   // 196608 B
  float* bn1     = (float*)(ws + 196608);                          // 128 f
  float* bn2     = bn1 + 128;                                      // 128 f
  int*   prog    = (int*)(ws + 198656);                            // 16 ints
  int*   cnt     = prog + 16;                                      // 4 ints
  float* sums1   = (float*)(ws + 198784);                          // 128 f
  float* sums2   = (float*)(ws + 199296);                          // 8 x 128 f
  float* sums3   = (float*)(ws + 203392);                          // 8 x 256 f (ends 211584)
  unsigned short* y1 = (unsigned short*)(ws + 4392960);            // 64 MB bf16
  unsigned short* y2 = (unsigned short*)(ws + 4392960 + 67108864); // 64 MB bf16 (K-permuted)
  // mn/mx alias y1 (dead after layer2); y1 rewritten by head before any read next replay
  float* mnbuf = (float*)(ws + 4392960);
  float* mxbuf = (float*)(ws + 4392960 + 8388608);

  // zero prog flags + counters + all atomic-accumulated sums each replay
  hipMemsetAsync(prog, 0, 12928, stream);
  head_kernel<<<B_ + NWORK, 512, 0, stream>>>(xyz, pts, W1, b1, g1, be1, out0, new_xyz,
                                              prog, cnt, y1, sums1, bn1);
  layer2_kernel<<<PNB, 256, 0, stream>>>(y1, W2, b2, bn1, g2, be2, y2, sums2, cnt, bn2);
  l3fused_kernel<<<PNB, 256, 0, stream>>>(y2, W3, b3, bn2, mnbuf, mxbuf, sums3);
  l3final_kernel<<<8192, 256, 0, stream>>>(sums3, g3, be3, mnbuf, mxbuf, out1);
}